// Round 6
// baseline (148.129 us; speedup 1.0000x reference)
//
#include <hip/hip_runtime.h>
#include <hip/hip_bf16.h>
#include <stdint.h>

typedef __attribute__((ext_vector_type(8))) short short8;
typedef __attribute__((ext_vector_type(4))) float f32x4;

#define NROWS  8192
#define DDIM   256
#define HHEADS 4
#define KTOT   1024            // H * D
#define BM     256
#define BN     256
#define BK     64
#define NT     (KTOT / BK)     // 16 K-tiles
#define NTB    (NROWS / BM)    // 32 tile rows
#define NTRI   (NTB * (NTB + 1) / 2)   // 528 triangular tiles

// LDS element offsets (unsigned short units) within one 32K-elem buffer:
//   A-lo: +0      (rows   0..127 x 64)
//   A-hi: +8192   (rows 128..255 x 64)
//   B-lo: +16384
//   B-hi: +24576
// buf b at b*32768 elems. Total 65536 elems = 128 KiB.

#define SBAR()  __builtin_amdgcn_s_barrier()
#define LGKM0() do { asm volatile("s_waitcnt lgkmcnt(0)" ::: "memory"); \
                     __builtin_amdgcn_sched_barrier(0); } while (0)
#define VMCNT(n) do { asm volatile("s_waitcnt vmcnt(" #n ")" ::: "memory"); \
                      __builtin_amdgcn_sched_barrier(0); } while (0)

__device__ __forceinline__ unsigned short f2bf(float f) {
  union { float f; uint32_t u; } v;
  v.f = f;
  uint32_t u = v.u;
  uint32_t r = (u + 0x7fffu + ((u >> 16) & 1u)) >> 16;
  return (unsigned short)r;
}

// --------------------------------------------------------------------------
// Kernel 1: Y[n, h*256+d] = bf16-normalized per-head scaled rows
// --------------------------------------------------------------------------
__global__ __launch_bounds__(256) void prep_y(const float* __restrict__ x,
                                              const float* __restrict__ av,
                                              unsigned short* __restrict__ Y) {
  __shared__ float a_sh[HHEADS][DDIM];
  __shared__ float red[4][HHEADS];

  const int t = threadIdx.x;
  #pragma unroll
  for (int h = 0; h < HHEADS; ++h) a_sh[h][t] = av[h * DDIM + t];
  __syncthreads();

  const int n = blockIdx.x;
  const float xd = x[(size_t)n * DDIM + t];

  float p[HHEADS], s[HHEADS];
  #pragma unroll
  for (int h = 0; h < HHEADS; ++h) { p[h] = a_sh[h][t] * xd; s[h] = p[h] * p[h]; }

  #pragma unroll
  for (int off = 32; off > 0; off >>= 1) {
    #pragma unroll
    for (int h = 0; h < HHEADS; ++h) s[h] += __shfl_xor(s[h], off, 64);
  }

  const int wave = t >> 6, lane = t & 63;
  if (lane == 0) {
    #pragma unroll
    for (int h = 0; h < HHEADS; ++h) red[wave][h] = s[h];
  }
  __syncthreads();

  #pragma unroll
  for (int h = 0; h < HHEADS; ++h) {
    const float sum = red[0][h] + red[1][h] + red[2][h] + red[3][h];
    const float rn = rsqrtf(fmaxf(sum, 1e-12f));
    Y[(size_t)n * KTOT + h * DDIM + t] = f2bf(p[h] * rn);
  }
}

// --------------------------------------------------------------------------
// stage one 128x64 bf16 half-tile: 2 x global_load_lds(16B) per thread.
// Linear LDS dest + inverse-swizzled global source (rule #21); the slot-XOR
// matches the ds_read swizzle (0 bank conflicts, proven r1-r3).
// --------------------------------------------------------------------------
__device__ __forceinline__ void stage_half(const unsigned short* __restrict__ Y,
                                           unsigned short* lds_region,
                                           int grow0, int k0, int tid) {
  #pragma unroll
  for (int i = 0; i < 2; ++i) {
    const int s    = i * 512 + tid;       // 16B slot 0..1023
    const int srow = s >> 3;              // 0..127
    const int gsl  = (s & 7) ^ (srow & 7);
    const unsigned short* gsrc =
        Y + (size_t)(grow0 + srow) * KTOT + k0 + gsl * 8;
    __builtin_amdgcn_global_load_lds(
        (const __attribute__((address_space(1))) void*)gsrc,
        (__attribute__((address_space(3))) void*)(lds_region + s * 8), 16, 0, 0);
  }
}

// --------------------------------------------------------------------------
// Kernel 2: C = Y*Y^T / 4 on triangular 256x256 tile grid, 8-phase schedule.
// 8 waves (2M x 4N), per-wave output 128x64, BK=64, double-buffered 128K LDS.
// Ledger (group computing tile T, phases a-d = quadrants 0-3):
//   a: issue A-lo(T+1)->buf[T+1]   (vacated at group T-1 end barrier)
//   b: issue A-hi(T+1)->buf[T+1]
//   c: issue B-lo(T+2)->buf[T]     (B of buf[T] vacated after phase a)
//   d: issue B-hi(T+2)->buf[T]; vmcnt(4) -> K(T+1) complete, 2 halves fly
// --------------------------------------------------------------------------
__global__ __launch_bounds__(512, 2) void gemm_yyt(const unsigned short* __restrict__ Y,
                                                   float* __restrict__ C) {
  __shared__ __attribute__((aligned(16))) unsigned short lds[65536];  // 128 KiB

  // bijective XCD swizzle: 528 = 8 * 66
  const int orig = blockIdx.x;
  const int wgid = (orig & 7) * (NTRI / 8) + (orig >> 3);

  int by = (int)((sqrtf(8.0f * (float)wgid + 1.0f) - 1.0f) * 0.5f);
  while ((by + 1) * (by + 2) / 2 <= wgid) ++by;
  while (by * (by + 1) / 2 > wgid) --by;
  const int bx = wgid - by * (by + 1) / 2;

  const int tid  = threadIdx.x;
  const int lane = tid & 63;
  const int wv   = tid >> 6;
  const int wr   = wv >> 2;       // 0..1  (M)
  const int wn   = wv & 3;        // 0..3  (N)
  const int l15  = lane & 15;
  const int lh   = lane >> 4;     // 0..3

  const int rowA0 = by * BM;
  const int rowB0 = bx * BN;

  const int arow = wr * 128 + l15;   // local A row base
  const int brow = wn * 64 + l15;    // local B row base
  const int slA0 = (0 + lh) ^ (arow & 7), slA1 = (4 + lh) ^ (arow & 7);
  const int slB0 = (0 + lh) ^ (brow & 7), slB1 = (4 + lh) ^ (brow & 7);

  f32x4 acc[8][4];
  #pragma unroll
  for (int m = 0; m < 8; ++m)
    #pragma unroll
    for (int n = 0; n < 4; ++n) acc[m][n] = (f32x4){0.f, 0.f, 0.f, 0.f};

  // ---------------- prologue: K0 all 4 halves + B halves of K1 ----------
  stage_half(Y, lds + 0,             rowA0,       0,  tid);  // A-lo(0)
  stage_half(Y, lds + 8192,          rowA0 + 128, 0,  tid);  // A-hi(0)
  stage_half(Y, lds + 16384,         rowB0,       0,  tid);  // B-lo(0)
  stage_half(Y, lds + 24576,         rowB0 + 128, 0,  tid);  // B-hi(0)
  stage_half(Y, lds + 32768 + 16384, rowB0,       64, tid);  // B-lo(1)
  stage_half(Y, lds + 32768 + 24576, rowB0 + 128, 64, tid);  // B-hi(1)
  VMCNT(4);   // K0 complete; B(1) may fly
  SBAR();

  short8 bf[4][2], af[2][2];

#define READ_A(q) do {                                                        \
    _Pragma("unroll")                                                         \
    for (int mm = 0; mm < 2; ++mm) {                                          \
      const int r_ = arow + ((q) * 2 + mm) * 16;                              \
      af[mm][0] = *(const short8*)(lds + cur + r_ * 64 + slA0 * 8);           \
      af[mm][1] = *(const short8*)(lds + cur + r_ * 64 + slA1 * 8);           \
    }                                                                         \
  } while (0)

#define MFMA_QUAD(q) do {                                                     \
    __builtin_amdgcn_s_setprio(1);                                            \
    _Pragma("unroll")                                                         \
    for (int mm = 0; mm < 2; ++mm)                                            \
      _Pragma("unroll")                                                       \
      for (int n = 0; n < 4; ++n) {                                           \
        acc[(q)*2+mm][n] = __builtin_amdgcn_mfma_f32_16x16x32_bf16(           \
            af[mm][0], bf[n][0], acc[(q)*2+mm][n], 0, 0, 0);                  \
        acc[(q)*2+mm][n] = __builtin_amdgcn_mfma_f32_16x16x32_bf16(           \
            af[mm][1], bf[n][1], acc[(q)*2+mm][n], 0, 0, 0);                  \
      }                                                                       \
    __builtin_amdgcn_s_setprio(0);                                            \
  } while (0)

  for (int T = 0; T < NT; ++T) {
    const int cur = (T & 1) << 15;
    const int nxt = ((T + 1) & 1) << 15;
    const int k1  = (T + 1) * BK;
    const int k2  = (T + 2) * BK;

    // ---- phase a (quadrant 0): B frags + A m0,m1 ----
    if (T + 1 < NT) stage_half(Y, lds + nxt, rowA0, k1, tid);        // A-lo(T+1)
    #pragma unroll
    for (int n = 0; n < 4; ++n) {
      const int r_ = brow + n * 16;
      bf[n][0] = *(const short8*)(lds + cur + 16384 + r_ * 64 + slB0 * 8);
      bf[n][1] = *(const short8*)(lds + cur + 16384 + r_ * 64 + slB1 * 8);
    }
    READ_A(0);
    __builtin_amdgcn_sched_barrier(0);
    SBAR(); LGKM0();
    MFMA_QUAD(0);
    __builtin_amdgcn_sched_barrier(0);
    SBAR();

    // ---- phase b (quadrant 1) ----
    if (T + 1 < NT) stage_half(Y, lds + nxt + 8192, rowA0 + 128, k1, tid);  // A-hi(T+1)
    READ_A(1);
    __builtin_amdgcn_sched_barrier(0);
    SBAR(); LGKM0();
    MFMA_QUAD(1);
    __builtin_amdgcn_sched_barrier(0);
    SBAR();

    // ---- phase c (quadrant 2) ----
    if (T + 2 < NT) stage_half(Y, lds + cur + 16384, rowB0, k2, tid);       // B-lo(T+2)
    READ_A(2);
    __builtin_amdgcn_sched_barrier(0);
    SBAR(); LGKM0();
    MFMA_QUAD(2);
    __builtin_amdgcn_sched_barrier(0);
    SBAR();

    // ---- phase d (quadrant 3) ----
    if (T + 2 < NT) stage_half(Y, lds + cur + 24576, rowB0 + 128, k2, tid); // B-hi(T+2)
    READ_A(3);
    __builtin_amdgcn_sched_barrier(0);
    SBAR(); LGKM0();
    MFMA_QUAD(3);
    __builtin_amdgcn_sched_barrier(0);
    if (T < NT - 2) { VMCNT(4); } else { VMCNT(0); }  // K(T+1) complete
    SBAR();
  }

  // ---------------- epilogue ----------------
  // mirror first (stores drain behind later work), straight write last.
  if (by != bx) {
    float (*tr)[257] = (float(*)[257])lds;   // 64 x 257 f32 = 65.8 KB
    #pragma unroll
    for (int s = 0; s < 4; ++s) {
      if (s > 0) __syncthreads();
      if (wn == s) {
        #pragma unroll
        for (int m = 0; m < 8; ++m)
          #pragma unroll
          for (int n = 0; n < 4; ++n)
            #pragma unroll
            for (int r = 0; r < 4; ++r) {
              const int cl = n * 16 + l15;                      // 0..63
              const int rl = wr * 128 + m * 16 + lh * 4 + r;    // 0..255
              tr[cl][rl] = acc[m][n][r];
            }
      }
      __syncthreads();
      #pragma unroll
      for (int q = 0; q < 8; ++q) {
        const int idx = q * 512 + tid;        // 0..4095
        const int ii  = idx >> 6;             // 0..63
        const int jj  = (idx & 63) * 4;       // 0..252
        f32x4 v = { tr[ii][jj] * 0.25f, tr[ii][jj + 1] * 0.25f,
                    tr[ii][jj + 2] * 0.25f, tr[ii][jj + 3] * 0.25f };
        *(f32x4*)(C + (size_t)(rowB0 + s * 64 + ii) * NROWS + rowA0 + jj) = v;
      }
    }
  }

  // straight write: row = rowA0 + wr*128 + m*16 + lh*4 + r, col = rowB0 + wn*64 + n*16 + l15
  const int crow0 = rowA0 + wr * 128;
  const int ccol  = rowB0 + wn * 64 + l15;
  #pragma unroll
  for (int m = 0; m < 8; ++m)
    #pragma unroll
    for (int n = 0; n < 4; ++n)
      #pragma unroll
      for (int r = 0; r < 4; ++r) {
        const int row = crow0 + m * 16 + lh * 4 + r;
        C[(size_t)row * NROWS + ccol + n * 16] = acc[m][n][r] * 0.25f;
      }
}

// --------------------------------------------------------------------------
extern "C" void kernel_launch(void* const* d_in, const int* in_sizes, int n_in,
                              void* d_out, int out_size, void* d_ws, size_t ws_size,
                              hipStream_t stream) {
  (void)in_sizes; (void)n_in; (void)out_size; (void)ws_size;
  const float* x  = (const float*)d_in[0];   // [8192, 256] f32
  const float* av = (const float*)d_in[1];   // [4, 256] f32
  float* C = (float*)d_out;                  // [8192, 8192] f32
  unsigned short* Y = (unsigned short*)d_ws; // [8192, 1024] bf16 scratch

  prep_y<<<NROWS, 256, 0, stream>>>(x, av, Y);
  gemm_yyt<<<NTRI, 512, 0, stream>>>(Y, C);
}

// Round 7
// 148.030 us; speedup vs baseline: 1.0007x; 1.0007x over previous
//
#include <hip/hip_runtime.h>
#include <hip/hip_bf16.h>
#include <stdint.h>

typedef __attribute__((ext_vector_type(8))) short short8;
typedef __attribute__((ext_vector_type(4))) float f32x4;

#define NROWS  8192
#define DDIM   256
#define HHEADS 4
#define KTOT   1024            // H * D
#define BM     256
#define BN     256
#define BK     64
#define NT     (KTOT / BK)     // 16 K-tiles
#define NTB    (NROWS / BM)    // 32 tile rows
#define NTRI   (NTB * (NTB + 1) / 2)   // 528 triangular tiles

// LDS element offsets (unsigned short units) within one 32K-elem buffer:
//   A-lo: +0      (rows   0..127 x 64)
//   A-hi: +8192   (rows 128..255 x 64)
//   B-lo: +16384
//   B-hi: +24576
// buf b at b*32768 elems. Total 65536 elems = 128 KiB.

#define SBAR()  __builtin_amdgcn_s_barrier()
#define LGKM0() do { asm volatile("s_waitcnt lgkmcnt(0)" ::: "memory"); \
                     __builtin_amdgcn_sched_barrier(0); } while (0)
#define VMCNT(n) do { asm volatile("s_waitcnt vmcnt(" #n ")" ::: "memory"); \
                      __builtin_amdgcn_sched_barrier(0); } while (0)

__device__ __forceinline__ unsigned short f2bf(float f) {
  union { float f; uint32_t u; } v;
  v.f = f;
  uint32_t u = v.u;
  uint32_t r = (u + 0x7fffu + ((u >> 16) & 1u)) >> 16;
  return (unsigned short)r;
}

// --------------------------------------------------------------------------
// Kernel 1: Y[n, h*256+d] = bf16-normalized per-head scaled rows
// --------------------------------------------------------------------------
__global__ __launch_bounds__(256) void prep_y(const float* __restrict__ x,
                                              const float* __restrict__ av,
                                              unsigned short* __restrict__ Y) {
  __shared__ float a_sh[HHEADS][DDIM];
  __shared__ float red[4][HHEADS];

  const int t = threadIdx.x;
  #pragma unroll
  for (int h = 0; h < HHEADS; ++h) a_sh[h][t] = av[h * DDIM + t];
  __syncthreads();

  const int n = blockIdx.x;
  const float xd = x[(size_t)n * DDIM + t];

  float p[HHEADS], s[HHEADS];
  #pragma unroll
  for (int h = 0; h < HHEADS; ++h) { p[h] = a_sh[h][t] * xd; s[h] = p[h] * p[h]; }

  #pragma unroll
  for (int off = 32; off > 0; off >>= 1) {
    #pragma unroll
    for (int h = 0; h < HHEADS; ++h) s[h] += __shfl_xor(s[h], off, 64);
  }

  const int wave = t >> 6, lane = t & 63;
  if (lane == 0) {
    #pragma unroll
    for (int h = 0; h < HHEADS; ++h) red[wave][h] = s[h];
  }
  __syncthreads();

  #pragma unroll
  for (int h = 0; h < HHEADS; ++h) {
    const float sum = red[0][h] + red[1][h] + red[2][h] + red[3][h];
    const float rn = rsqrtf(fmaxf(sum, 1e-12f));
    Y[(size_t)n * KTOT + h * DDIM + t] = f2bf(p[h] * rn);
  }
}

// --------------------------------------------------------------------------
// stage one 128x64 bf16 half-tile: 2 x global_load_lds(16B) per thread.
// Linear LDS dest + inverse-swizzled global source (rule #21); the slot-XOR
// matches the ds_read swizzle (0 bank conflicts, proven r1-r3).
// --------------------------------------------------------------------------
__device__ __forceinline__ void stage_half(const unsigned short* __restrict__ Y,
                                           unsigned short* lds_region,
                                           int grow0, int k0, int tid) {
  #pragma unroll
  for (int i = 0; i < 2; ++i) {
    const int s    = i * 512 + tid;       // 16B slot 0..1023
    const int srow = s >> 3;              // 0..127
    const int gsl  = (s & 7) ^ (srow & 7);
    const unsigned short* gsrc =
        Y + (size_t)(grow0 + srow) * KTOT + k0 + gsl * 8;
    __builtin_amdgcn_global_load_lds(
        (const __attribute__((address_space(1))) void*)gsrc,
        (__attribute__((address_space(3))) void*)(lds_region + s * 8), 16, 0, 0);
  }
}

// --------------------------------------------------------------------------
// Kernel 2: C = Y*Y^T / 4 on triangular 256x256 tile grid, 8-phase schedule.
// 8 waves (2M x 4N), per-wave output 128x64, BK=64, double-buffered 128K LDS.
// Ledger (group computing tile T, phases a-d = quadrants 0-3):
//   a: issue A-lo(T+1)->buf[T+1]   (vacated at group T-1 end barrier)
//   b: issue A-hi(T+1)->buf[T+1]
//   c: issue B-lo(T+2)->buf[T]     (B of buf[T] vacated after phase a)
//   d: issue B-hi(T+2)->buf[T]; vmcnt(4) -> K(T+1) complete, 2 halves fly
// --------------------------------------------------------------------------
__global__ __launch_bounds__(512, 2) void gemm_yyt(const unsigned short* __restrict__ Y,
                                                   float* __restrict__ C) {
  __shared__ __attribute__((aligned(16))) unsigned short lds[65536];  // 128 KiB

  // bijective XCD swizzle: 528 = 8 * 66
  const int orig = blockIdx.x;
  const int wgid = (orig & 7) * (NTRI / 8) + (orig >> 3);

  int by = (int)((sqrtf(8.0f * (float)wgid + 1.0f) - 1.0f) * 0.5f);
  while ((by + 1) * (by + 2) / 2 <= wgid) ++by;
  while (by * (by + 1) / 2 > wgid) --by;
  const int bx = wgid - by * (by + 1) / 2;

  const int tid  = threadIdx.x;
  const int lane = tid & 63;
  const int wv   = tid >> 6;
  const int wr   = wv >> 2;       // 0..1  (M)
  const int wn   = wv & 3;        // 0..3  (N)
  const int l15  = lane & 15;
  const int lh   = lane >> 4;     // 0..3

  const int rowA0 = by * BM;
  const int rowB0 = bx * BN;

  const int arow = wr * 128 + l15;   // local A row base
  const int brow = wn * 64 + l15;    // local B row base
  const int slA0 = (0 + lh) ^ (arow & 7), slA1 = (4 + lh) ^ (arow & 7);
  const int slB0 = (0 + lh) ^ (brow & 7), slB1 = (4 + lh) ^ (brow & 7);

  f32x4 acc[8][4];
  #pragma unroll
  for (int m = 0; m < 8; ++m)
    #pragma unroll
    for (int n = 0; n < 4; ++n) acc[m][n] = (f32x4){0.f, 0.f, 0.f, 0.f};

  // ---------------- prologue: K0 all 4 halves + B halves of K1 ----------
  stage_half(Y, lds + 0,             rowA0,       0,  tid);  // A-lo(0)
  stage_half(Y, lds + 8192,          rowA0 + 128, 0,  tid);  // A-hi(0)
  stage_half(Y, lds + 16384,         rowB0,       0,  tid);  // B-lo(0)
  stage_half(Y, lds + 24576,         rowB0 + 128, 0,  tid);  // B-hi(0)
  stage_half(Y, lds + 32768 + 16384, rowB0,       64, tid);  // B-lo(1)
  stage_half(Y, lds + 32768 + 24576, rowB0 + 128, 64, tid);  // B-hi(1)
  VMCNT(4);   // K0 complete; B(1) may fly
  SBAR();

  short8 bf[4][2], af[2][2];

#define READ_A(q) do {                                                        \
    _Pragma("unroll")                                                         \
    for (int mm = 0; mm < 2; ++mm) {                                          \
      const int r_ = arow + ((q) * 2 + mm) * 16;                              \
      af[mm][0] = *(const short8*)(lds + cur + r_ * 64 + slA0 * 8);           \
      af[mm][1] = *(const short8*)(lds + cur + r_ * 64 + slA1 * 8);           \
    }                                                                         \
  } while (0)

#define MFMA_QUAD(q) do {                                                     \
    __builtin_amdgcn_s_setprio(1);                                            \
    _Pragma("unroll")                                                         \
    for (int mm = 0; mm < 2; ++mm)                                            \
      _Pragma("unroll")                                                       \
      for (int n = 0; n < 4; ++n) {                                           \
        acc[(q)*2+mm][n] = __builtin_amdgcn_mfma_f32_16x16x32_bf16(           \
            af[mm][0], bf[n][0], acc[(q)*2+mm][n], 0, 0, 0);                  \
        acc[(q)*2+mm][n] = __builtin_amdgcn_mfma_f32_16x16x32_bf16(           \
            af[mm][1], bf[n][1], acc[(q)*2+mm][n], 0, 0, 0);                  \
      }                                                                       \
    __builtin_amdgcn_s_setprio(0);                                            \
  } while (0)

  for (int T = 0; T < NT; ++T) {
    const int cur = (T & 1) << 15;
    const int nxt = ((T + 1) & 1) << 15;
    const int k1  = (T + 1) * BK;
    const int k2  = (T + 2) * BK;

    // ---- phase a (quadrant 0): B frags + A m0,m1 ----
    if (T + 1 < NT) stage_half(Y, lds + nxt, rowA0, k1, tid);        // A-lo(T+1)
    #pragma unroll
    for (int n = 0; n < 4; ++n) {
      const int r_ = brow + n * 16;
      bf[n][0] = *(const short8*)(lds + cur + 16384 + r_ * 64 + slB0 * 8);
      bf[n][1] = *(const short8*)(lds + cur + 16384 + r_ * 64 + slB1 * 8);
    }
    READ_A(0);
    __builtin_amdgcn_sched_barrier(0);
    SBAR(); LGKM0();
    MFMA_QUAD(0);
    __builtin_amdgcn_sched_barrier(0);
    SBAR();

    // ---- phase b (quadrant 1) ----
    if (T + 1 < NT) stage_half(Y, lds + nxt + 8192, rowA0 + 128, k1, tid);  // A-hi(T+1)
    READ_A(1);
    __builtin_amdgcn_sched_barrier(0);
    SBAR(); LGKM0();
    MFMA_QUAD(1);
    __builtin_amdgcn_sched_barrier(0);
    SBAR();

    // ---- phase c (quadrant 2) ----
    if (T + 2 < NT) stage_half(Y, lds + cur + 16384, rowB0, k2, tid);       // B-lo(T+2)
    READ_A(2);
    __builtin_amdgcn_sched_barrier(0);
    SBAR(); LGKM0();
    MFMA_QUAD(2);
    __builtin_amdgcn_sched_barrier(0);
    SBAR();

    // ---- phase d (quadrant 3) ----
    if (T + 2 < NT) stage_half(Y, lds + cur + 24576, rowB0 + 128, k2, tid); // B-hi(T+2)
    READ_A(3);
    __builtin_amdgcn_sched_barrier(0);
    SBAR(); LGKM0();
    MFMA_QUAD(3);
    __builtin_amdgcn_sched_barrier(0);
    if (T < NT - 2) { VMCNT(4); } else { VMCNT(0); }  // K(T+1) complete
    SBAR();
  }

  // ---------------- epilogue ----------------
  // mirror first (stores drain behind later work), straight write last.
  if (by != bx) {
    float (*tr)[257] = (float(*)[257])lds;   // 64 x 257 f32 = 65.8 KB
    #pragma unroll
    for (int s = 0; s < 4; ++s) {
      if (s > 0) __syncthreads();
      if (wn == s) {
        #pragma unroll
        for (int m = 0; m < 8; ++m)
          #pragma unroll
          for (int n = 0; n < 4; ++n)
            #pragma unroll
            for (int r = 0; r < 4; ++r) {
              const int cl = n * 16 + l15;                      // 0..63
              const int rl = wr * 128 + m * 16 + lh * 4 + r;    // 0..255
              tr[cl][rl] = acc[m][n][r];
            }
      }
      __syncthreads();
      #pragma unroll
      for (int q = 0; q < 8; ++q) {
        const int idx = q * 512 + tid;        // 0..4095
        const int ii  = idx >> 6;             // 0..63
        const int jj  = (idx & 63) * 4;       // 0..252
        f32x4 v = { tr[ii][jj] * 0.25f, tr[ii][jj + 1] * 0.25f,
                    tr[ii][jj + 2] * 0.25f, tr[ii][jj + 3] * 0.25f };
        *(f32x4*)(C + (size_t)(rowB0 + s * 64 + ii) * NROWS + rowA0 + jj) = v;
      }
    }
  }

  // straight write: row = rowA0 + wr*128 + m*16 + lh*4 + r, col = rowB0 + wn*64 + n*16 + l15
  const int crow0 = rowA0 + wr * 128;
  const int ccol  = rowB0 + wn * 64 + l15;
  #pragma unroll
  for (int m = 0; m < 8; ++m)
    #pragma unroll
    for (int n = 0; n < 4; ++n)
      #pragma unroll
      for (int r = 0; r < 4; ++r) {
        const int row = crow0 + m * 16 + lh * 4 + r;
        C[(size_t)row * NROWS + ccol + n * 16] = acc[m][n][r] * 0.25f;
      }
}

// --------------------------------------------------------------------------
extern "C" void kernel_launch(void* const* d_in, const int* in_sizes, int n_in,
                              void* d_out, int out_size, void* d_ws, size_t ws_size,
                              hipStream_t stream) {
  (void)in_sizes; (void)n_in; (void)out_size; (void)ws_size;
  const float* x  = (const float*)d_in[0];   // [8192, 256] f32
  const float* av = (const float*)d_in[1];   // [4, 256] f32
  float* C = (float*)d_out;                  // [8192, 8192] f32
  unsigned short* Y = (unsigned short*)d_ws; // [8192, 1024] bf16 scratch

  prep_y<<<NROWS, 256, 0, stream>>>(x, av, Y);
  gemm_yyt<<<NTRI, 512, 0, stream>>>(Y, C);
}

// Round 8
// 128.808 us; speedup vs baseline: 1.1500x; 1.1492x over previous
//
#include <hip/hip_runtime.h>
#include <hip/hip_bf16.h>
#include <stdint.h>

typedef __attribute__((ext_vector_type(8))) short short8;
typedef __attribute__((ext_vector_type(4))) float f32x4;

#define NROWS  8192
#define DDIM   256
#define HHEADS 4
#define KTOT   1024            // H * D
#define BM     256
#define BN     256
#define BK     64
#define NT     (KTOT / BK)     // 16 K-tiles
#define NTB    (NROWS / BM)    // 32 tile rows
#define NOFF   (NTB * (NTB - 1) / 2)   // 496 strict-lower tiles
#define NBLK   (NOFF + NTB / 2)        // 512 blocks = exactly 2 rounds

// LDS element offsets (unsigned short units) within one 32K-elem buffer:
//   A-lo: +0, A-hi: +8192, B-lo: +16384, B-hi: +24576; buf b at b*32768.

#define SBAR()  __builtin_amdgcn_s_barrier()
#define LGKM0() do { asm volatile("s_waitcnt lgkmcnt(0)" ::: "memory"); \
                     __builtin_amdgcn_sched_barrier(0); } while (0)
#define VMCNT(n) do { asm volatile("s_waitcnt vmcnt(" #n ")" ::: "memory"); \
                      __builtin_amdgcn_sched_barrier(0); } while (0)

__device__ __forceinline__ unsigned short f2bf(float f) {
  union { float f; uint32_t u; } v;
  v.f = f;
  uint32_t u = v.u;
  uint32_t r = (u + 0x7fffu + ((u >> 16) & 1u)) >> 16;
  return (unsigned short)r;
}

// --------------------------------------------------------------------------
// Kernel 1: Y[n, h*256+d] = bf16-normalized per-head scaled rows
// --------------------------------------------------------------------------
__global__ __launch_bounds__(256) void prep_y(const float* __restrict__ x,
                                              const float* __restrict__ av,
                                              unsigned short* __restrict__ Y) {
  __shared__ float a_sh[HHEADS][DDIM];
  __shared__ float red[4][HHEADS];

  const int t = threadIdx.x;
  #pragma unroll
  for (int h = 0; h < HHEADS; ++h) a_sh[h][t] = av[h * DDIM + t];
  __syncthreads();

  const int n = blockIdx.x;
  const float xd = x[(size_t)n * DDIM + t];

  float p[HHEADS], s[HHEADS];
  #pragma unroll
  for (int h = 0; h < HHEADS; ++h) { p[h] = a_sh[h][t] * xd; s[h] = p[h] * p[h]; }

  #pragma unroll
  for (int off = 32; off > 0; off >>= 1) {
    #pragma unroll
    for (int h = 0; h < HHEADS; ++h) s[h] += __shfl_xor(s[h], off, 64);
  }

  const int wave = t >> 6, lane = t & 63;
  if (lane == 0) {
    #pragma unroll
    for (int h = 0; h < HHEADS; ++h) red[wave][h] = s[h];
  }
  __syncthreads();

  #pragma unroll
  for (int h = 0; h < HHEADS; ++h) {
    const float sum = red[0][h] + red[1][h] + red[2][h] + red[3][h];
    const float rn = rsqrtf(fmaxf(sum, 1e-12f));
    Y[(size_t)n * KTOT + h * DDIM + t] = f2bf(p[h] * rn);
  }
}

// --------------------------------------------------------------------------
// stage one 128x64 bf16 half-tile: 2 x global_load_lds(16B) per thread.
// Linear LDS dest + inverse-swizzled global source (rule #21).
// --------------------------------------------------------------------------
__device__ __forceinline__ void stage_half(const unsigned short* __restrict__ Y,
                                           unsigned short* lds_region,
                                           int grow0, int k0, int tid) {
  #pragma unroll
  for (int i = 0; i < 2; ++i) {
    const int s    = i * 512 + tid;       // 16B slot 0..1023
    const int srow = s >> 3;              // 0..127
    const int gsl  = (s & 7) ^ (srow & 7);
    const unsigned short* gsrc =
        Y + (size_t)(grow0 + srow) * KTOT + k0 + gsl * 8;
    __builtin_amdgcn_global_load_lds(
        (const __attribute__((address_space(1))) void*)gsrc,
        (__attribute__((address_space(3))) void*)(lds_region + s * 8), 16, 0, 0);
  }
}

// --------------------------------------------------------------------------
// One 256x256 output tile: prologue + 8-phase K-loop + epilogue.
// Ledger (group computing tile T, phases a-d = quadrants 0-3):
//   a: issue A-lo(T+1)->buf[T+1]; b: A-hi(T+1)->buf[T+1]
//   c: B-lo(T+2)->buf[T];        d: B-hi(T+2)->buf[T]; vmcnt(4)
// --------------------------------------------------------------------------
__device__ __forceinline__ void run_tile(const unsigned short* __restrict__ Y,
                                         float* __restrict__ C,
                                         unsigned short* lds,
                                         int by, int bx,
                                         int tid, int lane, int wr, int wn,
                                         int l15, int lh) {
  const int rowA0 = by * BM;
  const int rowB0 = bx * BN;

  const int arow = wr * 128 + l15;   // local A row base
  const int brow = wn * 64 + l15;    // local B row base
  const int slA0 = (0 + lh) ^ (arow & 7), slA1 = (4 + lh) ^ (arow & 7);
  const int slB0 = (0 + lh) ^ (brow & 7), slB1 = (4 + lh) ^ (brow & 7);

  f32x4 acc[8][4];
  #pragma unroll
  for (int m = 0; m < 8; ++m)
    #pragma unroll
    for (int n = 0; n < 4; ++n) acc[m][n] = (f32x4){0.f, 0.f, 0.f, 0.f};

  // prologue: K0 all 4 halves + B halves of K1
  stage_half(Y, lds + 0,             rowA0,       0,  tid);  // A-lo(0)
  stage_half(Y, lds + 8192,          rowA0 + 128, 0,  tid);  // A-hi(0)
  stage_half(Y, lds + 16384,         rowB0,       0,  tid);  // B-lo(0)
  stage_half(Y, lds + 24576,         rowB0 + 128, 0,  tid);  // B-hi(0)
  stage_half(Y, lds + 32768 + 16384, rowB0,       64, tid);  // B-lo(1)
  stage_half(Y, lds + 32768 + 24576, rowB0 + 128, 64, tid);  // B-hi(1)
  VMCNT(4);   // K0 complete; B(1) may fly
  SBAR();

  short8 bf[4][2], af[2][2];

#define READ_A(q) do {                                                        \
    _Pragma("unroll")                                                         \
    for (int mm = 0; mm < 2; ++mm) {                                          \
      const int r_ = arow + ((q) * 2 + mm) * 16;                              \
      af[mm][0] = *(const short8*)(lds + cur + r_ * 64 + slA0 * 8);           \
      af[mm][1] = *(const short8*)(lds + cur + r_ * 64 + slA1 * 8);           \
    }                                                                         \
  } while (0)

#define MFMA_QUAD(q) do {                                                     \
    __builtin_amdgcn_s_setprio(1);                                            \
    _Pragma("unroll")                                                         \
    for (int mm = 0; mm < 2; ++mm)                                            \
      _Pragma("unroll")                                                       \
      for (int n = 0; n < 4; ++n) {                                           \
        acc[(q)*2+mm][n] = __builtin_amdgcn_mfma_f32_16x16x32_bf16(           \
            af[mm][0], bf[n][0], acc[(q)*2+mm][n], 0, 0, 0);                  \
        acc[(q)*2+mm][n] = __builtin_amdgcn_mfma_f32_16x16x32_bf16(           \
            af[mm][1], bf[n][1], acc[(q)*2+mm][n], 0, 0, 0);                  \
      }                                                                       \
    __builtin_amdgcn_s_setprio(0);                                            \
  } while (0)

  for (int T = 0; T < NT; ++T) {
    const int cur = (T & 1) << 15;
    const int nxt = ((T + 1) & 1) << 15;
    const int k1  = (T + 1) * BK;
    const int k2  = (T + 2) * BK;

    // ---- phase a (quadrant 0): B frags + A m0,m1 ----
    if (T + 1 < NT) stage_half(Y, lds + nxt, rowA0, k1, tid);        // A-lo(T+1)
    #pragma unroll
    for (int n = 0; n < 4; ++n) {
      const int r_ = brow + n * 16;
      bf[n][0] = *(const short8*)(lds + cur + 16384 + r_ * 64 + slB0 * 8);
      bf[n][1] = *(const short8*)(lds + cur + 16384 + r_ * 64 + slB1 * 8);
    }
    READ_A(0);
    __builtin_amdgcn_sched_barrier(0);
    SBAR(); LGKM0();
    MFMA_QUAD(0);
    __builtin_amdgcn_sched_barrier(0);
    SBAR();

    // ---- phase b (quadrant 1) ----
    if (T + 1 < NT) stage_half(Y, lds + nxt + 8192, rowA0 + 128, k1, tid);
    READ_A(1);
    __builtin_amdgcn_sched_barrier(0);
    SBAR(); LGKM0();
    MFMA_QUAD(1);
    __builtin_amdgcn_sched_barrier(0);
    SBAR();

    // ---- phase c (quadrant 2) ----
    if (T + 2 < NT) stage_half(Y, lds + cur + 16384, rowB0, k2, tid);
    READ_A(2);
    __builtin_amdgcn_sched_barrier(0);
    SBAR(); LGKM0();
    MFMA_QUAD(2);
    __builtin_amdgcn_sched_barrier(0);
    SBAR();

    // ---- phase d (quadrant 3) ----
    if (T + 2 < NT) stage_half(Y, lds + cur + 24576, rowB0 + 128, k2, tid);
    READ_A(3);
    __builtin_amdgcn_sched_barrier(0);
    SBAR(); LGKM0();
    MFMA_QUAD(3);
    __builtin_amdgcn_sched_barrier(0);
    if (T < NT - 2) { VMCNT(4); } else { VMCNT(0); }  // K(T+1) complete
    SBAR();
  }

  // ---- straight write first: stores drain under the mirror's LDS work ----
  const int crow0 = rowA0 + wr * 128;
  const int ccol  = rowB0 + wn * 64 + l15;
  #pragma unroll
  for (int m = 0; m < 8; ++m)
    #pragma unroll
    for (int n = 0; n < 4; ++n)
      #pragma unroll
      for (int r = 0; r < 4; ++r) {
        const int row = crow0 + m * 16 + lh * 4 + r;
        C[(size_t)row * NROWS + ccol + n * 16] = acc[m][n][r] * 0.25f;
      }

  // ---- mirror write via LDS transpose (off-diagonal tiles only) ----
  // SBAR + LGKM0 instead of __syncthreads: the hazards are LDS-only, and
  // __syncthreads would drain vmcnt (i.e. wait on the straight-write stores).
  if (by != bx) {
    float (*tr)[257] = (float(*)[257])lds;   // 64 x 257 f32
    #pragma unroll
    for (int s = 0; s < 4; ++s) {
      if (s > 0) SBAR();                 // slice s-1 readers done
      if (wn == s) {
        #pragma unroll
        for (int m = 0; m < 8; ++m)
          #pragma unroll
          for (int n = 0; n < 4; ++n)
            #pragma unroll
            for (int r = 0; r < 4; ++r) {
              const int cl = n * 16 + l15;                      // 0..63
              const int rl = wr * 128 + m * 16 + lh * 4 + r;    // 0..255
              tr[cl][rl] = acc[m][n][r];
            }
        LGKM0();                          // my ds_writes visible
      }
      SBAR();
      #pragma unroll
      for (int q = 0; q < 8; ++q) {
        const int idx = q * 512 + tid;        // 0..4095
        const int ii  = idx >> 6;             // 0..63
        const int jj  = (idx & 63) * 4;       // 0..252
        f32x4 v = { tr[ii][jj] * 0.25f, tr[ii][jj + 1] * 0.25f,
                    tr[ii][jj + 2] * 0.25f, tr[ii][jj + 3] * 0.25f };
        *(f32x4*)(C + (size_t)(rowB0 + s * 64 + ii) * NROWS + rowA0 + jj) = v;
      }
    }
  }
#undef READ_A
#undef MFMA_QUAD
}

// --------------------------------------------------------------------------
// Kernel 2: C = Y*Y^T / 4.  512 blocks = exactly 2 rounds at 1 block/CU:
//   blocks 0..15   : TWO diagonal tiles each (2i, 2i+1) — launched first,
//                    cheaper per tile (no mirror), so not the critical path.
//   blocks 16..511 : one strict-lower tile each (496 = 8*62, XCD-swizzled).
// No inter-rep sync needed: final VMCNT(0)+SBAR of rep 1 drains everything,
// and barriers are collective so no wave can run ahead of the pack.
// --------------------------------------------------------------------------
__global__ __launch_bounds__(512, 2) void gemm_yyt(const unsigned short* __restrict__ Y,
                                                   float* __restrict__ C) {
  __shared__ __attribute__((aligned(16))) unsigned short lds[65536];  // 128 KiB

  const int orig = blockIdx.x;
  int by, bx;
  bool two = false;
  if (orig < NTB / 2) {
    by = bx = orig * 2;
    two = true;
  } else {
    const int o2 = orig - NTB / 2;              // 0..495
    const int wg = (o2 & 7) * (NOFF / 8) + (o2 >> 3);   // bijective XCD swizzle
    int b = (int)((sqrtf(8.0f * (float)wg + 1.0f) + 1.0f) * 0.5f);
    while (b * (b - 1) / 2 > wg) --b;
    while ((b + 1) * b / 2 <= wg) ++b;
    by = b;
    bx = wg - b * (b - 1) / 2;                  // 0 <= bx < by
  }

  const int tid  = threadIdx.x;
  const int lane = tid & 63;
  const int wv   = tid >> 6;
  const int wr   = wv >> 2;       // 0..1  (M)
  const int wn   = wv & 3;        // 0..3  (N)
  const int l15  = lane & 15;
  const int lh   = lane >> 4;     // 0..3

  run_tile(Y, C, lds, by, bx, tid, lane, wr, wn, l15, lh);
  if (two)
    run_tile(Y, C, lds, by + 1, bx + 1, tid, lane, wr, wn, l15, lh);
}

// --------------------------------------------------------------------------
extern "C" void kernel_launch(void* const* d_in, const int* in_sizes, int n_in,
                              void* d_out, int out_size, void* d_ws, size_t ws_size,
                              hipStream_t stream) {
  (void)in_sizes; (void)n_in; (void)out_size; (void)ws_size;
  const float* x  = (const float*)d_in[0];   // [8192, 256] f32
  const float* av = (const float*)d_in[1];   // [4, 256] f32
  float* C = (float*)d_out;                  // [8192, 8192] f32
  unsigned short* Y = (unsigned short*)d_ws; // [8192, 1024] bf16 scratch

  prep_y<<<NROWS, 256, 0, stream>>>(x, av, Y);
  gemm_yyt<<<NBLK, 512, 0, stream>>>(Y, C);
}